// Round 1
// baseline (16528.583 us; speedup 1.0000x reference)
//
#include <hip/hip_runtime.h>

typedef __bf16 bf16_t;
typedef bf16_t bf16x8 __attribute__((ext_vector_type(8)));
typedef float f32x4 __attribute__((ext_vector_type(4)));

#define B_SZ 256
#define T_SZ 512
#define I_SZ 64
#define H_SZ 256

struct Job {
  const bf16_t* wih;      // [1024, Kin] row-major (N=gate row, K)
  const bf16_t* whh_hi;   // [1024, 256]
  const bf16_t* whh_lo;   // [1024, 256]
  const float*  bias;     // [1024] = b_ih + b_hh
  const bf16_t* h_in;     // [256,256] bf16 (double-buffered)
  bf16_t*       h_out;    // [256,256]
  float*        c_state;  // [256,256] fp32, in-place (lane-owned)
  const float*  x32;      // layer0 input x [B,T,64] fp32, or null
  const bf16_t* x16;      // layer1 input h0 [T,B,512] bf16, or null
  bf16_t*       hout;     // h0 destination base (t,dir pre-offset), or null
  int t;
  int Kin;
};

__device__ __forceinline__ float sigm(float x) { return 1.f / (1.f + __expf(-x)); }
__device__ __forceinline__ float tanhx(float x) {
  x = fminf(fmaxf(x, -15.f), 15.f);
  float e = __expf(-2.f * x);
  return (1.f - e) / (1.f + e);
}

// Block = 256 threads = 4 waves. grid.x = 16 batch-tiles * 4 col-chunks.
// Wave w owns h-cols [chunk*64 + w*16, +16) for batch rows [bt*16, +16).
// Each wave computes all 4 gate strips for its cols -> i/f/g/o combine is
// lane-local in the MFMA C/D layout (col=lane&15, row=quad*4+reg). No LDS.
__global__ __launch_bounds__(256) void lstm_step(Job jA, Job jB) {
  Job jb = (blockIdx.y == 0) ? jA : jB;
  const int lane = threadIdx.x & 63;
  const int wv   = threadIdx.x >> 6;
  const int bt   = blockIdx.x >> 2;
  const int ch   = blockIdx.x & 3;
  const int jcol = ch * 64 + wv * 16;
  const int b0   = bt * 16;
  const int l15  = lane & 15;
  const int quad = lane >> 4;
  const int koff = quad * 8;
  const int wrow0 = jcol + l15;  // B-operand n = lane&15

  f32x4 acc[4] = {{0,0,0,0},{0,0,0,0},{0,0,0,0},{0,0,0,0}};

  if (jb.x32) {  // layer 0: x fp32 [B,T,64], convert to bf16 frags
    const float* xr = jb.x32 + ((size_t)(b0 + l15) * T_SZ + jb.t) * I_SZ;
#pragma unroll
    for (int kt = 0; kt < I_SZ; kt += 32) {
      const float* px = xr + kt + koff;
      float4 u0 = *(const float4*)(px);
      float4 u1 = *(const float4*)(px + 4);
      bf16x8 a;
      a[0]=(bf16_t)u0.x; a[1]=(bf16_t)u0.y; a[2]=(bf16_t)u0.z; a[3]=(bf16_t)u0.w;
      a[4]=(bf16_t)u1.x; a[5]=(bf16_t)u1.y; a[6]=(bf16_t)u1.z; a[7]=(bf16_t)u1.w;
#pragma unroll
      for (int g = 0; g < 4; ++g) {
        bf16x8 w = *(const bf16x8*)(jb.wih + (size_t)(g*H_SZ + wrow0) * I_SZ + kt + koff);
        acc[g] = __builtin_amdgcn_mfma_f32_16x16x32_bf16(a, w, acc[g], 0, 0, 0);
      }
    }
  } else {       // layer 1: h0 bf16 [T,B,512]
    const bf16_t* xr = jb.x16 + ((size_t)jb.t * B_SZ + (b0 + l15)) * 512;
#pragma unroll 4
    for (int kt = 0; kt < 512; kt += 32) {
      bf16x8 a = *(const bf16x8*)(xr + kt + koff);
#pragma unroll
      for (int g = 0; g < 4; ++g) {
        bf16x8 w = *(const bf16x8*)(jb.wih + (size_t)(g*H_SZ + wrow0) * 512 + kt + koff);
        acc[g] = __builtin_amdgcn_mfma_f32_16x16x32_bf16(a, w, acc[g], 0, 0, 0);
      }
    }
  }

  // recurrent: h @ (Whh_hi + Whh_lo)^T  (hi/lo split kills systematic W error)
  {
    const bf16_t* hr = jb.h_in + (size_t)(b0 + l15) * H_SZ;
#pragma unroll 2
    for (int kt = 0; kt < H_SZ; kt += 32) {
      bf16x8 a = *(const bf16x8*)(hr + kt + koff);
#pragma unroll
      for (int g = 0; g < 4; ++g) {
        size_t wo = (size_t)(g*H_SZ + wrow0) * H_SZ + kt + koff;
        acc[g] = __builtin_amdgcn_mfma_f32_16x16x32_bf16(a, *(const bf16x8*)(jb.whh_hi + wo), acc[g], 0, 0, 0);
        acc[g] = __builtin_amdgcn_mfma_f32_16x16x32_bf16(a, *(const bf16x8*)(jb.whh_lo + wo), acc[g], 0, 0, 0);
      }
    }
  }

  const int j = jcol + l15;      // D col = lane&15 -> h column this lane owns
  const float bi = jb.bias[j];
  const float bf_ = jb.bias[H_SZ + j];
  const float bg = jb.bias[2*H_SZ + j];
  const float bo = jb.bias[3*H_SZ + j];
#pragma unroll
  for (int r = 0; r < 4; ++r) {
    const int b = b0 + quad * 4 + r;   // D row = quad*4 + reg
    float iv = sigm(acc[0][r] + bi);
    float fv = sigm(acc[1][r] + bf_);
    float gv = tanhx(acc[2][r] + bg);
    float ov = sigm(acc[3][r] + bo);
    size_t idx = (size_t)b * H_SZ + j;
    float cn = fv * jb.c_state[idx] + iv * gv;
    jb.c_state[idx] = cn;
    float hn = ov * tanhx(cn);
    bf16_t hb = (bf16_t)hn;
    jb.h_out[idx] = hb;
    if (jb.hout) jb.hout[(size_t)b * 512 + j] = hb;
  }
}

__global__ void k_cvt(const float* __restrict__ s, bf16_t* __restrict__ d, int n) {
  int i = blockIdx.x * 256 + threadIdx.x;
  if (i < n) d[i] = (bf16_t)s[i];
}
__global__ void k_split(const float* __restrict__ s, bf16_t* __restrict__ hi,
                        bf16_t* __restrict__ lo, int n) {
  int i = blockIdx.x * 256 + threadIdx.x;
  if (i < n) {
    float v = s[i];
    bf16_t h = (bf16_t)v;
    hi[i] = h;
    lo[i] = (bf16_t)(v - (float)h);
  }
}
__global__ void k_bias(const float* __restrict__ a, const float* __restrict__ b,
                       float* __restrict__ d, int n) {
  int i = blockIdx.x * 256 + threadIdx.x;
  if (i < n) d[i] = a[i] + b[i];
}
__global__ void k_zero(bf16_t* h, float* c, int nh, int nc) {
  int i = blockIdx.x * 256 + threadIdx.x;
  if (i < nh) h[i] = (bf16_t)0.f;
  if (i < nc) c[i] = 0.f;
}
__global__ void k_fc(const bf16_t* __restrict__ hf, const bf16_t* __restrict__ hb,
                     const float* __restrict__ fw, const float* __restrict__ fb,
                     float* __restrict__ out) {
  int b = threadIdx.x;
  float s = fb[0];
  const bf16_t* pf = hf + (size_t)b * H_SZ;
  const bf16_t* pb = hb + (size_t)b * H_SZ;
  for (int j = 0; j < H_SZ; ++j) s += fw[j] * (float)pf[j];
  for (int j = 0; j < H_SZ; ++j) s += fw[H_SZ + j] * (float)pb[j];
  out[b] = s;
}

extern "C" void kernel_launch(void* const* d_in, const int* in_sizes, int n_in,
                              void* d_out, int out_size, void* d_ws, size_t ws_size,
                              hipStream_t stream) {
  (void)in_sizes; (void)n_in; (void)out_size; (void)ws_size;
  const float* x      = (const float*)d_in[0];
  const float* wih[4] = {(const float*)d_in[1], (const float*)d_in[5],
                         (const float*)d_in[9], (const float*)d_in[13]};
  const float* whh[4] = {(const float*)d_in[2], (const float*)d_in[6],
                         (const float*)d_in[10], (const float*)d_in[14]};
  const float* bih[4] = {(const float*)d_in[3], (const float*)d_in[7],
                         (const float*)d_in[11], (const float*)d_in[15]};
  const float* bhh[4] = {(const float*)d_in[4], (const float*)d_in[8],
                         (const float*)d_in[12], (const float*)d_in[16]};
  const float* fcw = (const float*)d_in[17];
  const float* fcb = (const float*)d_in[18];
  float* out = (float*)d_out;

  // ---- workspace carve (all 256B aligned) ----
  char* p = (char*)d_ws;
  auto take = [&](size_t bytes) { char* r = p; p += (bytes + 255) & ~(size_t)255; return r; };
  const int KinL[4] = {I_SZ, I_SZ, 512, 512};   // jobs: l0f, l0b, l1f, l1b
  bf16_t* wihb[4]; bf16_t* whhhi[4]; bf16_t* whhlo[4]; float* biasc[4];
  for (int k = 0; k < 4; ++k) {
    wihb[k]  = (bf16_t*)take((size_t)1024 * KinL[k] * 2);
    whhhi[k] = (bf16_t*)take((size_t)1024 * 256 * 2);
    whhlo[k] = (bf16_t*)take((size_t)1024 * 256 * 2);
    biasc[k] = (float*)take(1024 * 4);
  }
  bf16_t* hst = (bf16_t*)take((size_t)8 * 65536 * 2);  // [job][buf 0/1][256*256]
  float*  cst = (float*)take((size_t)4 * 65536 * 4);   // [job][256*256]
  bf16_t* h0  = (bf16_t*)take((size_t)T_SZ * B_SZ * 512 * 2);  // [T][B][2H] 128 MiB

  // ---- prep: weight conversion / hi-lo split / bias combine / zero state ----
  for (int k = 0; k < 4; ++k) {
    int n = 1024 * KinL[k];
    k_cvt<<<dim3((n + 255) / 256), 256, 0, stream>>>(wih[k], wihb[k], n);
    k_split<<<dim3(1024), 256, 0, stream>>>(whh[k], whhhi[k], whhlo[k], 1024 * 256);
    k_bias<<<dim3(4), 256, 0, stream>>>(bih[k], bhh[k], biasc[k], 1024);
  }
  k_zero<<<dim3(2048), 256, 0, stream>>>(hst, cst, 8 * 65536, 4 * 65536);

  auto mkjob = [&](int job, int s, int t) {
    Job j;
    j.wih = wihb[job]; j.whh_hi = whhhi[job]; j.whh_lo = whhlo[job];
    j.bias = biasc[job];
    j.h_in  = hst + (size_t)job * 131072 + (size_t)(s & 1) * 65536;
    j.h_out = hst + (size_t)job * 131072 + (size_t)((s + 1) & 1) * 65536;
    j.c_state = cst + (size_t)job * 65536;
    j.x32 = (job < 2) ? x : nullptr;
    j.x16 = (job < 2) ? nullptr : h0;
    j.t = t;
    j.Kin = KinL[job];
    if (job == 0)      j.hout = h0 + (size_t)t * (B_SZ * 512);
    else if (job == 1) j.hout = h0 + (size_t)t * (B_SZ * 512) + 256;
    else               j.hout = nullptr;
    return j;
  };

  // ---- layer 0: fwd (t=s) and bwd (t=511-s) in one launch per step ----
  for (int s = 0; s < T_SZ; ++s) {
    Job j0 = mkjob(0, s, s);
    Job j1 = mkjob(1, s, T_SZ - 1 - s);
    lstm_step<<<dim3(64, 2), 256, 0, stream>>>(j0, j1);
  }
  // ---- layer 1: fwd full scan; bwd is ONE step (time-aligned reverse scan
  //      output at t=T-1 = first reverse step from zero state) ----
  for (int s = 0; s < T_SZ; ++s) {
    Job j0 = mkjob(2, s, s);
    if (s == 0) {
      Job j1 = mkjob(3, 0, T_SZ - 1);
      lstm_step<<<dim3(64, 2), 256, 0, stream>>>(j0, j1);
    } else {
      lstm_step<<<dim3(64, 1), 256, 0, stream>>>(j0, j0);
    }
  }

  // final h: l1f ends in buf (512&1)=0; l1b single step wrote buf 1
  const bf16_t* h1f = hst + (size_t)2 * 131072;
  const bf16_t* h1b = hst + (size_t)3 * 131072 + 65536;
  k_fc<<<dim3(1), 256, 0, stream>>>(h1f, h1b, fcw, fcb, out);
}